// Round 1
// baseline (282.837 us; speedup 1.0000x reference)
//
#include <hip/hip_runtime.h>

// QLIFSpike: x[B,T,C,H,W] f32, mask[B,T,C] i32 -> spikes[B,T,C,H,W] f32
// Sequential over T per (b,c,h,w); parallel over B*C*H*W.
// Constants from reference: TAU=0.5, THRESH=1.0, LB=-3, UB_LEVEL=1, INTERVAL=1.

#define T_STEPS 10
#define C_CH    128
#define HW_SZ   1024   // 32*32

__device__ __forceinline__ float qlif_step(float& mem, float xi) {
    mem = mem * 0.5f + xi;                       // leaky integrate (mul by 0.5 exact)
    float spike = (mem > 1.0f) ? 1.0f : 0.0f;    // threshold fire
    float m = (spike > 0.0f) ? 0.0f : mem;       // hard reset
    // qmem: clip(round(m), -3, 1); rintf == round-half-to-even == np.round
    mem = fminf(fmaxf(rintf(m), -3.0f), 1.0f);
    return spike;
}

__global__ __launch_bounds__(256) void qlif_kernel(
        const float* __restrict__ x,
        const int*   __restrict__ mask,
        float*       __restrict__ out,
        int n_vec)   // B*C*HW/4
{
    int v = blockIdx.x * blockDim.x + threadIdx.x;
    if (v >= n_vec) return;

    const int HW4 = HW_SZ / 4;                   // 256 vec4 per (b,c)
    int hw4 = v & (HW4 - 1);
    int bc  = v >> 8;                            // v / 256
    int c   = bc & (C_CH - 1);
    int b   = bc >> 7;                           // bc / 128

    // element offset of (b, t=0, c, hw4*4)
    long base    = ((long)b * T_STEPS * C_CH + c) * HW_SZ + (long)hw4 * 4;
    int  mbase   = b * T_STEPS * C_CH + c;
    const long tstride = (long)C_CH * HW_SZ;     // 131072 elements per t

    float4 mem = make_float4(0.f, 0.f, 0.f, 0.f);

    #pragma unroll
    for (int t = 0; t < T_STEPS; ++t) {
        float m = (float)mask[mbase + t * C_CH]; // wave-uniform, 0 or 1 (exact)
        const float4 xi = *reinterpret_cast<const float4*>(x + base + t * tstride);
        float4 s;
        s.x = qlif_step(mem.x, xi.x * m);
        s.y = qlif_step(mem.y, xi.y * m);
        s.z = qlif_step(mem.z, xi.z * m);
        s.w = qlif_step(mem.w, xi.w * m);
        *reinterpret_cast<float4*>(out + base + t * tstride) = s;
    }
}

extern "C" void kernel_launch(void* const* d_in, const int* in_sizes, int n_in,
                              void* d_out, int out_size, void* d_ws, size_t ws_size,
                              hipStream_t stream) {
    const float* x    = (const float*)d_in[0];
    const int*   mask = (const int*)d_in[1];
    // d_in[2] (conv_input) is unused by the reference computation.
    float* out = (float*)d_out;

    // n_vec = B*C*HW/4 ; B derived from total element count for safety
    long total = (long)in_sizes[0];                       // B*T*C*HW
    int  B     = (int)(total / ((long)T_STEPS * C_CH * HW_SZ));
    int  n_vec = (int)((long)B * C_CH * HW_SZ / 4);

    int block = 256;
    int grid  = (n_vec + block - 1) / block;
    qlif_kernel<<<grid, block, 0, stream>>>(x, mask, out, n_vec);
}

// Round 2
// 271.444 us; speedup vs baseline: 1.0420x; 1.0420x over previous
//
#include <hip/hip_runtime.h>

// QLIFSpike: x[B,T,C,H,W] f32, mask[B,T,C] i32 -> spikes[B,T,C,H,W] f32
// Sequential over T per (b,c,h,w); parallel over B*C*H*W.
// Constants from reference: TAU=0.5, THRESH=1.0, LB=-3, UB_LEVEL=1, INTERVAL=1.
//
// R2: pure-streaming tuning. x/out are touched exactly once -> nontemporal
// (nt) loads/stores to avoid polluting L2; all 10 mask values preloaded so
// every VMEM op issues before the serial membrane recurrence.

#define T_STEPS 10
#define C_CH    128
#define HW_SZ   1024   // 32*32

typedef float vfloat4 __attribute__((ext_vector_type(4)));

__device__ __forceinline__ float qlif_step(float& mem, float xi) {
    mem = mem * 0.5f + xi;                       // leaky integrate (×0.5 exact)
    float spike = (mem > 1.0f) ? 1.0f : 0.0f;    // threshold fire
    float m = (spike > 0.0f) ? 0.0f : mem;       // hard reset
    // qmem: clip(round(m), -3, 1); rintf == round-half-to-even == np.round
    mem = fminf(fmaxf(rintf(m), -3.0f), 1.0f);
    return spike;
}

__global__ __launch_bounds__(256) void qlif_kernel(
        const float* __restrict__ x,
        const int*   __restrict__ mask,
        float*       __restrict__ out,
        int n_vec)   // B*C*HW/4
{
    int v = blockIdx.x * blockDim.x + threadIdx.x;
    if (v >= n_vec) return;

    const int HW4 = HW_SZ / 4;                   // 256 vec4 per (b,c)
    int hw4 = v & (HW4 - 1);
    int bc  = v >> 8;                            // v / 256
    int c   = bc & (C_CH - 1);
    int b   = bc >> 7;                           // bc / 128

    // element offset of (b, t=0, c, hw4*4)
    long base  = ((long)b * T_STEPS * C_CH + c) * HW_SZ + (long)hw4 * 4;
    int  mbase = b * T_STEPS * C_CH + c;
    const long tstride = (long)C_CH * HW_SZ;     // 131072 elements per t

    // Preload all mask values (independent of the recurrence; tiny, L1/L2-hot)
    float mval[T_STEPS];
    #pragma unroll
    for (int t = 0; t < T_STEPS; ++t)
        mval[t] = (float)mask[mbase + t * C_CH];

    float4 mem = make_float4(0.f, 0.f, 0.f, 0.f);

    #pragma unroll
    for (int t = 0; t < T_STEPS; ++t) {
        const vfloat4* xp = reinterpret_cast<const vfloat4*>(x + base + t * tstride);
        vfloat4 xi = __builtin_nontemporal_load(xp);
        float m = mval[t];
        vfloat4 s;
        s.x = qlif_step(mem.x, xi.x * m);
        s.y = qlif_step(mem.y, xi.y * m);
        s.z = qlif_step(mem.z, xi.z * m);
        s.w = qlif_step(mem.w, xi.w * m);
        vfloat4* op = reinterpret_cast<vfloat4*>(out + base + t * tstride);
        __builtin_nontemporal_store(s, op);
    }
}

extern "C" void kernel_launch(void* const* d_in, const int* in_sizes, int n_in,
                              void* d_out, int out_size, void* d_ws, size_t ws_size,
                              hipStream_t stream) {
    const float* x    = (const float*)d_in[0];
    const int*   mask = (const int*)d_in[1];
    // d_in[2] (conv_input) is unused by the reference computation.
    float* out = (float*)d_out;

    long total = (long)in_sizes[0];                       // B*T*C*HW
    int  B     = (int)(total / ((long)T_STEPS * C_CH * HW_SZ));
    int  n_vec = (int)((long)B * C_CH * HW_SZ / 4);

    int block = 256;
    int grid  = (n_vec + block - 1) / block;
    qlif_kernel<<<grid, block, 0, stream>>>(x, mask, out, n_vec);
}

// Round 3
// 264.832 us; speedup vs baseline: 1.0680x; 1.0250x over previous
//
#include <hip/hip_runtime.h>

// QLIFSpike: x[B,T,C,H,W] f32, mask[B,T,C] i32 -> spikes[B,T,C,H,W] f32
// Sequential over T per (b,c,h,w); parallel over B*C*H*W.
// Constants from reference: TAU=0.5, THRESH=1.0, LB=-3, UB_LEVEL=1, INTERVAL=1.
//
// R3: mask-aware load skipping. Post-qmem mem ∈ {-3..1}; with mask==0 the
// step is mem=mem*0.5 ∈ [-1.5,0.5] -> spike always 0 and no x needed.
// mask is wave-uniform (wave covers hw within one (b,c)) -> readfirstlane
// makes the skip a scalar branch: whole wave omits the 16B/lane load.
// Expected: x read traffic halves (mask ~ Bernoulli(0.5)).

#define T_STEPS 10
#define C_CH    128
#define HW_SZ   1024   // 32*32

typedef float vfloat4 __attribute__((ext_vector_type(4)));

__device__ __forceinline__ float qlif_step(float& mem, float xi) {
    mem = mem * 0.5f + xi;                       // leaky integrate (×0.5 exact)
    float spike = (mem > 1.0f) ? 1.0f : 0.0f;    // threshold fire
    float m = (spike > 0.0f) ? 0.0f : mem;       // hard reset
    // qmem: clip(round(m), -3, 1); rintf == round-half-to-even == np.round
    mem = fminf(fmaxf(rintf(m), -3.0f), 1.0f);
    return spike;
}

__global__ __launch_bounds__(256) void qlif_kernel(
        const float* __restrict__ x,
        const int*   __restrict__ mask,
        float*       __restrict__ out,
        int n_vec)   // B*C*HW/4
{
    int v = blockIdx.x * blockDim.x + threadIdx.x;
    if (v >= n_vec) return;

    const int HW4 = HW_SZ / 4;                   // 256 vec4 per (b,c)
    int hw4 = v & (HW4 - 1);
    int bc  = v >> 8;                            // v / 256
    int c   = bc & (C_CH - 1);
    int b   = bc >> 7;                           // bc / 128

    // element offset of (b, t=0, c, hw4*4)
    long base  = ((long)b * T_STEPS * C_CH + c) * HW_SZ + (long)hw4 * 4;
    int  mbase = b * T_STEPS * C_CH + c;
    const long tstride = (long)C_CH * HW_SZ;     // 131072 elements per t

    // Preload all mask values into SGPRs (wave-uniform: whole wave shares (b,c)).
    int mval[T_STEPS];
    #pragma unroll
    for (int t = 0; t < T_STEPS; ++t)
        mval[t] = __builtin_amdgcn_readfirstlane(mask[mbase + t * C_CH]);

    float4 mem = make_float4(0.f, 0.f, 0.f, 0.f);

    #pragma unroll
    for (int t = 0; t < T_STEPS; ++t) {
        vfloat4 s;
        if (mval[t] != 0) {
            // active step: load x, full LIF update
            const vfloat4* xp = reinterpret_cast<const vfloat4*>(x + base + t * tstride);
            vfloat4 xi = __builtin_nontemporal_load(xp);
            s.x = qlif_step(mem.x, xi.x);
            s.y = qlif_step(mem.y, xi.y);
            s.z = qlif_step(mem.z, xi.z);
            s.w = qlif_step(mem.w, xi.w);
        } else {
            // masked step: xi=0 -> mem=mem*0.5 <= 0.5 -> no spike, no reset;
            // qmem still applies (round-half-even, clip is no-op here)
            mem.x = rintf(mem.x * 0.5f);
            mem.y = rintf(mem.y * 0.5f);
            mem.z = rintf(mem.z * 0.5f);
            mem.w = rintf(mem.w * 0.5f);
            s.x = 0.f; s.y = 0.f; s.z = 0.f; s.w = 0.f;
        }
        vfloat4* op = reinterpret_cast<vfloat4*>(out + base + t * tstride);
        __builtin_nontemporal_store(s, op);
    }
}

extern "C" void kernel_launch(void* const* d_in, const int* in_sizes, int n_in,
                              void* d_out, int out_size, void* d_ws, size_t ws_size,
                              hipStream_t stream) {
    const float* x    = (const float*)d_in[0];
    const int*   mask = (const int*)d_in[1];
    // d_in[2] (conv_input) is unused by the reference computation.
    float* out = (float*)d_out;

    long total = (long)in_sizes[0];                       // B*T*C*HW
    int  B     = (int)(total / ((long)T_STEPS * C_CH * HW_SZ));
    int  n_vec = (int)((long)B * C_CH * HW_SZ / 4);

    int block = 256;
    int grid  = (n_vec + block - 1) / block;
    qlif_kernel<<<grid, block, 0, stream>>>(x, mask, out, n_vec);
}